// Round 8
// baseline (175.676 us; speedup 1.0000x reference)
//
#include <hip/hip_runtime.h>
#include <cstdint>

typedef unsigned short u16;

#define NTOK 2048
#define DMODEL 1024
#define NHEAD 16
#define NOFF 44

typedef __attribute__((ext_vector_type(8))) short bf16x8;
typedef __attribute__((ext_vector_type(4))) float f32x4;

__device__ __forceinline__ u16 f2bf(float f) {
  uint32_t u = __builtin_bit_cast(uint32_t, f);
  u = (u + 0x7FFFu + ((u >> 16) & 1u)) >> 16;
  return (u16)u;
}
__device__ __forceinline__ float bf2f(u16 u) {
  return __builtin_bit_cast(float, ((uint32_t)u) << 16);
}

// ---------------- merged fp32 -> bf16 convert ----------------
__global__ __launch_bounds__(256) void cvt_all_kernel(
    const float* __restrict__ x, const float* __restrict__ wq,
    const float* __restrict__ wg, const float* __restrict__ wo,
    u16* __restrict__ xb, u16* __restrict__ wqb,
    u16* __restrict__ wgb, u16* __restrict__ wob) {
  int i = blockIdx.x * 256 + threadIdx.x;
  const float* in; u16* out; int off;
  if (i < 524288) { in = x; out = xb; off = 0; }
  else if (i < 524288 + 786432) { in = wq; out = wqb; off = 524288; }
  else if (i < 524288 + 786432 + 262144) { in = wg; out = wgb; off = 524288 + 786432; }
  else { in = wo; out = wob; off = 524288 + 786432 + 262144; }
  int j = i - off;
  float4 f = reinterpret_cast<const float4*>(in)[j];
  ushort4 o;
  o.x = f2bf(f.x); o.y = f2bf(f.y); o.z = f2bf(f.z); o.w = f2bf(f.w);
  reinterpret_cast<ushort4*>(out)[j] = o;
}

// ---------------- async global->LDS 16B ----------------
__device__ __forceinline__ void async16(const void* g, void* l) {
  __builtin_amdgcn_global_load_lds(
      (const __attribute__((address_space(1))) void*)g,
      (__attribute__((address_space(3))) void*)l,
      16, 0, 0);
}

// A-tile: XOR-swizzled LDS, BK=128 (16 chunks of 16 B per row; physical
// chunk p of row r holds global chunk p ^ (r & 15)). B operand: NOT staged —
// fragments loaded straight global->VGPR (b128, 64 B-contiguous per row,
// L2-hot, independent of the LDS barrier so they pipeline across it).
// This halves the per-CU ds_read_b128 pipe demand, the binding resource.

// ---------------- fused [qkv|gate] GEMM ----------------
// C = x @ [Wqkv;Wgate]^T, 128x128 tiles, BK=128, grid (32,16).
// cols [0,3072) -> bf16 qkv (+bqkv); cols [3072,4096) -> bf16 sigmoid gate.
__global__ __launch_bounds__(256) void gemm_fused(
    const u16* __restrict__ A, const u16* __restrict__ B,
    const float* __restrict__ bqkv, const float* __restrict__ bgate,
    u16* __restrict__ qkvb, u16* __restrict__ gateb) {
  __shared__ __align__(16) u16 As[128 * 128];
  const int tid = threadIdx.x;
  const int lane = tid & 63;
  const int w = tid >> 6;
  const int wm = w >> 1, wn = w & 1;
  const int wrow0 = wm * 64;
  const int tile_m = blockIdx.y * 128;
  const int tile_n = blockIdx.x * 128;
  const int l15 = lane & 15;
  const int quad = lane >> 4;

  f32x4 acc[4][4];
  const f32x4 zero = {0.f, 0.f, 0.f, 0.f};
#pragma unroll
  for (int mi = 0; mi < 4; ++mi)
#pragma unroll
    for (int ni = 0; ni < 4; ++ni) acc[mi][ni] = zero;

  // B-frag row base pointers (row = tile_n + wn*64 + ni*16 + l15)
  const u16* brow[4];
#pragma unroll
  for (int ni = 0; ni < 4; ++ni)
    brow[ni] = B + (size_t)(tile_n + wn * 64 + ni * 16 + l15) * 1024 + quad * 8;

  for (int k0 = 0; k0 < 1024; k0 += 128) {
    // stage A (swizzled)
#pragma unroll
    for (int c = 0; c < 8; ++c) {
      int idx = c * 256 + tid;
      int row = idx >> 4;
      int gcol = ((idx & 15) ^ (row & 15)) * 8;
      int lcol = (idx & 15) * 8;
      async16(A + (size_t)(tile_m + row) * 1024 + k0 + gcol, As + row * 128 + lcol);
    }
    // B-frags for all 4 ksteps: global->VGPR, independent of LDS/barrier
    bf16x8 bfr[4][4];
#pragma unroll
    for (int kk = 0; kk < 4; ++kk)
#pragma unroll
      for (int ni = 0; ni < 4; ++ni)
        bfr[kk][ni] = *(const bf16x8*)(brow[ni] + k0 + kk * 32);
    __syncthreads();

#pragma unroll
    for (int kk = 0; kk < 4; ++kk) {
      const int pc = ((kk * 4 + quad) ^ l15) * 8;
      bf16x8 af[4];
#pragma unroll
      for (int mi = 0; mi < 4; ++mi)
        af[mi] = *(const bf16x8*)(As + (wrow0 + mi * 16 + l15) * 128 + pc);
#pragma unroll
      for (int mi = 0; mi < 4; ++mi)
#pragma unroll
        for (int ni = 0; ni < 4; ++ni)
          acc[mi][ni] = __builtin_amdgcn_mfma_f32_16x16x32_bf16(
              af[mi], bfr[kk][ni], acc[mi][ni], 0, 0, 0);
    }
    __syncthreads();
  }

  const int r0 = tile_m + wrow0 + quad * 4;
  const int c0 = tile_n + wn * 64 + l15;
  const bool isGate = (tile_n >= 3072);  // block-uniform (3072 % 128 == 0)
  const float* bp = isGate ? bgate : bqkv;
  const int crel0 = isGate ? (c0 - 3072) : c0;
  const int nout = isGate ? 1024 : 3072;
  u16* outp = isGate ? gateb : qkvb;
#pragma unroll
  for (int mi = 0; mi < 4; ++mi) {
#pragma unroll
    for (int ni = 0; ni < 4; ++ni) {
      int col = crel0 + ni * 16;
      float bv = bp[col];
#pragma unroll
      for (int r = 0; r < 4; ++r) {
        float val = acc[mi][ni][r] + bv;
        if (isGate) val = 1.f / (1.f + __expf(-val));
        outp[(size_t)(r0 + mi * 16 + r) * nout + col] = f2bf(val);
      }
    }
  }
}

// ---------------- out GEMM: out = a2 @ Wout^T + bout (fp32) ----------------
// 128x64 tiles, BK=128, grid (16,16). B (Wout) direct from global.
__global__ __launch_bounds__(256) void gemm_out(
    const u16* __restrict__ A, const u16* __restrict__ B,
    const float* __restrict__ bias, float* __restrict__ C) {
  __shared__ __align__(16) u16 As[128 * 128];
  const int tid = threadIdx.x;
  const int lane = tid & 63;
  const int w = tid >> 6;
  const int tile_m = blockIdx.y * 128;
  const int tile_n = blockIdx.x * 64;
  const int l15 = lane & 15;
  const int quad = lane >> 4;

  f32x4 acc[2][4];
  const f32x4 zero = {0.f, 0.f, 0.f, 0.f};
#pragma unroll
  for (int mi = 0; mi < 2; ++mi)
#pragma unroll
    for (int ni = 0; ni < 4; ++ni) acc[mi][ni] = zero;

  const u16* brow[4];
#pragma unroll
  for (int ni = 0; ni < 4; ++ni)
    brow[ni] = B + (size_t)(tile_n + ni * 16 + l15) * 1024 + quad * 8;

  for (int k0 = 0; k0 < 1024; k0 += 128) {
#pragma unroll
    for (int c = 0; c < 8; ++c) {
      int idx = c * 256 + tid;
      int row = idx >> 4;
      int gcol = ((idx & 15) ^ (row & 15)) * 8;
      int lcol = (idx & 15) * 8;
      async16(A + (size_t)(tile_m + row) * 1024 + k0 + gcol, As + row * 128 + lcol);
    }
    bf16x8 bfr[4][4];
#pragma unroll
    for (int kk = 0; kk < 4; ++kk)
#pragma unroll
      for (int ni = 0; ni < 4; ++ni)
        bfr[kk][ni] = *(const bf16x8*)(brow[ni] + k0 + kk * 32);
    __syncthreads();

#pragma unroll
    for (int kk = 0; kk < 4; ++kk) {
      const int pc = ((kk * 4 + quad) ^ l15) * 8;
      bf16x8 af[2];
#pragma unroll
      for (int mi = 0; mi < 2; ++mi)
        af[mi] = *(const bf16x8*)(As + (w * 32 + mi * 16 + l15) * 128 + pc);
#pragma unroll
      for (int mi = 0; mi < 2; ++mi)
#pragma unroll
        for (int ni = 0; ni < 4; ++ni)
          acc[mi][ni] = __builtin_amdgcn_mfma_f32_16x16x32_bf16(
              af[mi], bfr[kk][ni], acc[mi][ni], 0, 0, 0);
    }
    __syncthreads();
  }

  const int r0 = tile_m + w * 32 + quad * 4;
  const int c0 = tile_n + l15;
#pragma unroll
  for (int mi = 0; mi < 2; ++mi) {
#pragma unroll
    for (int ni = 0; ni < 4; ++ni) {
      int col = c0 + ni * 16;
      float bv = bias[col];
#pragma unroll
      for (int r = 0; r < 4; ++r)
        C[(size_t)(r0 + mi * 16 + r) * 1024 + col] = acc[mi][ni][r] + bv;
    }
  }
}

// ---------------- MFMA attention (r3 version) ----------------
__global__ __launch_bounds__(256) void attn_mfma_kernel(
    const u16* __restrict__ qkv, const float* __restrict__ pos_bias,
    const u16* __restrict__ gate, u16* __restrict__ a2) {
  __shared__ __align__(16) u16 Pl[4][16][232];
  __shared__ float pbs[NOFF];
  const int tid = threadIdx.x;
  const int lane = tid & 63;
  const int w = tid >> 6;
  const int h = blockIdx.y;
  const int n0 = blockIdx.x * 64 + w * 16;
  const int quad = lane >> 4;
  const int l15 = lane & 15;

  if (tid < NOFF) pbs[tid] = pos_bias[tid * NHEAD + h];

  const int soffs[11] = {48, 64, 96, 128, 192, 256, 384, 512, 768, 1024, 1536};
  int gbase[14];
  gbase[0] = n0 - 32; gbase[1] = n0 - 16; gbase[2] = n0;
#pragma unroll
  for (int g = 0; g < 11; ++g) gbase[3 + g] = n0 - soffs[g];

  const u16* qbase = qkv + (size_t)(n0 + l15) * 3072 + h * 64 + quad * 8;
  bf16x8 aq0 = *(const bf16x8*)(qbase);
  bf16x8 aq1 = *(const bf16x8*)(qbase + 32);

  f32x4 s[14];
  const f32x4 zero = {0.f, 0.f, 0.f, 0.f};
#pragma unroll
  for (int g = 0; g < 14; ++g) {
    s[g] = zero;
    if (gbase[g] + 15 < 0) continue;
    int row = gbase[g] + l15;
    int rc = row < 0 ? 0 : row;
    const u16* kb = qkv + 1024 + (size_t)rc * 3072 + h * 64 + quad * 8;
    bf16x8 bk0 = *(const bf16x8*)(kb);
    bf16x8 bk1 = *(const bf16x8*)(kb + 32);
    s[g] = __builtin_amdgcn_mfma_f32_16x16x32_bf16(aq0, bk0, s[g], 0, 0, 0);
    s[g] = __builtin_amdgcn_mfma_f32_16x16x32_bf16(aq1, bk1, s[g], 0, 0, 0);
  }
  __syncthreads();  // pbs ready

#pragma unroll
  for (int g = 0; g < 14; ++g) {
    int key = gbase[g] + l15;
#pragma unroll
    for (int r = 0; r < 4; ++r) {
      int q = n0 + quad * 4 + r;
      int o = q - key;
      bool valid; int bidx;
      if (g < 3) {
        valid = (o >= 0) & (o <= 32) & (key >= 0);
        bidx = o < 0 ? 0 : (o > 32 ? 32 : o);
      } else {
        valid = (key >= 0) & (o == soffs[g - 3]);
        bidx = g + 30;
      }
      float val = s[g][r] * 0.125f + pbs[bidx];
      s[g][r] = valid ? val : -INFINITY;
    }
  }

  float rl[4];
#pragma unroll
  for (int r = 0; r < 4; ++r) {
    float mx = s[0][r];
#pragma unroll
    for (int g = 1; g < 14; ++g) mx = fmaxf(mx, s[g][r]);
    mx = fmaxf(mx, __shfl_xor(mx, 1, 64));
    mx = fmaxf(mx, __shfl_xor(mx, 2, 64));
    mx = fmaxf(mx, __shfl_xor(mx, 4, 64));
    mx = fmaxf(mx, __shfl_xor(mx, 8, 64));
    float sum = 0.f;
#pragma unroll
    for (int g = 0; g < 14; ++g) {
      float p = __expf(s[g][r] - mx);
      s[g][r] = p;
      sum += p;
    }
    sum += __shfl_xor(sum, 1, 64);
    sum += __shfl_xor(sum, 2, 64);
    sum += __shfl_xor(sum, 4, 64);
    sum += __shfl_xor(sum, 8, 64);
    rl[r] = 1.0f / sum;
  }

#pragma unroll
  for (int g = 0; g < 14; ++g)
#pragma unroll
    for (int r = 0; r < 4; ++r)
      Pl[w][quad * 4 + r][g * 16 + l15] = f2bf(s[g][r]);
  __syncthreads();

  f32x4 ov[4];
#pragma unroll
  for (int ni = 0; ni < 4; ++ni) ov[ni] = zero;
  const u16* vb = qkv + 2048 + h * 64;
#pragma unroll
  for (int kc = 0; kc < 7; ++kc) {
    if (gbase[2 * kc] + 15 < 0 && gbase[2 * kc + 1] + 15 < 0) continue;
    bf16x8 ap = *(const bf16x8*)(&Pl[w][l15][kc * 32 + quad * 8]);
    int g = kc * 2 + (quad >> 1);
    int keyg = gbase[g] + (quad & 1) * 8;
    const u16* rp[8];
#pragma unroll
    for (int j = 0; j < 8; ++j) {
      int row = keyg + j;
      rp[j] = vb + (size_t)(row < 0 ? 0 : row) * 3072;
    }
#pragma unroll
    for (int ni = 0; ni < 4; ++ni) {
      bf16x8 bv;
#pragma unroll
      for (int j = 0; j < 8; ++j) bv[j] = (short)rp[j][ni * 16 + l15];
      ov[ni] = __builtin_amdgcn_mfma_f32_16x16x32_bf16(ap, bv, ov[ni], 0, 0, 0);
    }
  }

#pragma unroll
  for (int ni = 0; ni < 4; ++ni) {
#pragma unroll
    for (int r = 0; r < 4; ++r) {
      int q = n0 + quad * 4 + r;
      int col = h * 64 + ni * 16 + l15;
      float o = ov[ni][r] * rl[r];
      float g = bf2f(gate[(size_t)q * DMODEL + col]);
      a2[(size_t)q * DMODEL + col] = f2bf(o * g);
    }
  }
}

extern "C" void kernel_launch(void* const* d_in, const int* in_sizes, int n_in,
                              void* d_out, int out_size, void* d_ws,
                              size_t ws_size, hipStream_t stream) {
  (void)in_sizes; (void)n_in; (void)out_size; (void)ws_size;
  const float* x = (const float*)d_in[0];
  const float* Wqkv = (const float*)d_in[1];
  const float* bqkv = (const float*)d_in[2];
  const float* Wout = (const float*)d_in[3];
  const float* bout = (const float*)d_in[4];
  const float* Wgate = (const float*)d_in[5];
  const float* bgate = (const float*)d_in[6];
  const float* pos_bias = (const float*)d_in[7];
  float* out = (float*)d_out;

  char* ws = (char*)d_ws;
  u16* xb    = (u16*)(ws);                    // [2048,1024]  4 MB
  u16* Wcat  = (u16*)(ws + (4u << 20));       // [4096,1024]  8 MB (Wqkv|Wgate)
  u16* Woutb = (u16*)(ws + (12u << 20));      // [1024,1024]  2 MB
  u16* qkvb  = (u16*)(ws + (14u << 20));      // [2048,3072] 12 MB
  u16* gate  = (u16*)(ws + (26u << 20));      // [2048,1024]  4 MB bf16
  u16* a2    = (u16*)(ws + (30u << 20));      // [2048,1024]  4 MB

  cvt_all_kernel<<<7168, 256, 0, stream>>>(
      x, Wqkv, Wgate, Wout, xb, Wcat, Wcat + 3072 * 1024, Woutb);

  // [qkv | gate] = x @ [Wqkv;Wgate]^T
  gemm_fused<<<dim3(32, 16), 256, 0, stream>>>(xb, Wcat, bqkv, bgate,
                                               qkvb, gate);
  // attention + gating -> a2 bf16 [2048, 1024]
  attn_mfma_kernel<<<dim3(32, 16), 256, 0, stream>>>(qkvb, pos_bias, gate, a2);
  // out = a2 @ Wout^T + bout -> fp32 [2048, 1024]
  gemm_out<<<dim3(16, 16), 256, 0, stream>>>(a2, Woutb, bout, out);
}

// Round 9
// 140.458 us; speedup vs baseline: 1.2507x; 1.2507x over previous
//
#include <hip/hip_runtime.h>
#include <cstdint>

typedef unsigned short u16;

#define NTOK 2048
#define DMODEL 1024
#define NHEAD 16
#define NOFF 44

typedef __attribute__((ext_vector_type(8))) short bf16x8;
typedef __attribute__((ext_vector_type(4))) float f32x4;

__device__ __forceinline__ u16 f2bf(float f) {
  uint32_t u = __builtin_bit_cast(uint32_t, f);
  u = (u + 0x7FFFu + ((u >> 16) & 1u)) >> 16;
  return (u16)u;
}
__device__ __forceinline__ float bf2f(u16 u) {
  return __builtin_bit_cast(float, ((uint32_t)u) << 16);
}

// ---------------- merged fp32 -> bf16 convert ----------------
__global__ __launch_bounds__(256) void cvt_all_kernel(
    const float* __restrict__ x, const float* __restrict__ wq,
    const float* __restrict__ wg, const float* __restrict__ wo,
    u16* __restrict__ xb, u16* __restrict__ wqb,
    u16* __restrict__ wgb, u16* __restrict__ wob) {
  int i = blockIdx.x * 256 + threadIdx.x;
  const float* in; u16* out; int off;
  if (i < 524288) { in = x; out = xb; off = 0; }
  else if (i < 524288 + 786432) { in = wq; out = wqb; off = 524288; }
  else if (i < 524288 + 786432 + 262144) { in = wg; out = wgb; off = 524288 + 786432; }
  else { in = wo; out = wob; off = 524288 + 786432 + 262144; }
  int j = i - off;
  float4 f = reinterpret_cast<const float4*>(in)[j];
  ushort4 o;
  o.x = f2bf(f.x); o.y = f2bf(f.y); o.z = f2bf(f.z); o.w = f2bf(f.w);
  reinterpret_cast<ushort4*>(out)[j] = o;
}

// ---------------- async global->LDS 16B ----------------
__device__ __forceinline__ void async16(const void* g, void* l) {
  __builtin_amdgcn_global_load_lds(
      (const __attribute__((address_space(1))) void*)g,
      (__attribute__((address_space(3))) void*)l,
      16, 0, 0);
}

// XOR-swizzled LDS tiles, BK=128 (rows of 128 u16 = 16 chunks of 16 B).
// LDS physical chunk p of row r holds global chunk p ^ (r & 15).
// Frag read of logical chunk g from row r reads physical g ^ (r & 15):
// a quad's 16 lanes cover 16 distinct chunks -> 2-way aliasing = free.
// Both operands staged via global_load_lds (r8 showed B-direct regresses:
// scattered 16-row b128 loads swamp the VMEM request pipe).

// ---------------- fused [qkv|gate] GEMM ----------------
// C = x @ [Wqkv;Wgate]^T, 128x128 tiles, BK=128, grid (32,16).
// cols [0,3072) -> bf16 qkv (+bqkv); cols [3072,4096) -> bf16 sigmoid gate.
__global__ __launch_bounds__(256) void gemm_fused(
    const u16* __restrict__ A, const u16* __restrict__ B,
    const float* __restrict__ bqkv, const float* __restrict__ bgate,
    u16* __restrict__ qkvb, u16* __restrict__ gateb) {
  __shared__ __align__(16) u16 As[128 * 128];
  __shared__ __align__(16) u16 Bs[128 * 128];
  const int tid = threadIdx.x;
  const int lane = tid & 63;
  const int w = tid >> 6;
  const int wm = w >> 1, wn = w & 1;
  const int wrow0 = wm * 64;
  const int tile_m = blockIdx.y * 128;
  const int tile_n = blockIdx.x * 128;
  const int l15 = lane & 15;
  const int quad = lane >> 4;

  f32x4 acc[4][4];
  const f32x4 zero = {0.f, 0.f, 0.f, 0.f};
#pragma unroll
  for (int mi = 0; mi < 4; ++mi)
#pragma unroll
    for (int ni = 0; ni < 4; ++ni) acc[mi][ni] = zero;

  for (int k0 = 0; k0 < 1024; k0 += 128) {
#pragma unroll
    for (int c = 0; c < 8; ++c) {
      int idx = c * 256 + tid;
      int row = idx >> 4;
      int gcol = ((idx & 15) ^ (row & 15)) * 8;  // swizzled global chunk
      int lcol = (idx & 15) * 8;                 // linear LDS chunk
      async16(A + (size_t)(tile_m + row) * 1024 + k0 + gcol, As + row * 128 + lcol);
      async16(B + (size_t)(tile_n + row) * 1024 + k0 + gcol, Bs + row * 128 + lcol);
    }
    __syncthreads();

#pragma unroll
    for (int kk = 0; kk < 4; ++kk) {
      const int pc = ((kk * 4 + quad) ^ l15) * 8;  // physical chunk offset
      bf16x8 af[4], bfr[4];
#pragma unroll
      for (int mi = 0; mi < 4; ++mi)
        af[mi] = *(const bf16x8*)(As + (wrow0 + mi * 16 + l15) * 128 + pc);
#pragma unroll
      for (int ni = 0; ni < 4; ++ni)
        bfr[ni] = *(const bf16x8*)(Bs + (wn * 64 + ni * 16 + l15) * 128 + pc);
#pragma unroll
      for (int mi = 0; mi < 4; ++mi)
#pragma unroll
        for (int ni = 0; ni < 4; ++ni)
          acc[mi][ni] = __builtin_amdgcn_mfma_f32_16x16x32_bf16(
              af[mi], bfr[ni], acc[mi][ni], 0, 0, 0);
    }
    __syncthreads();
  }

  const int r0 = tile_m + wrow0 + quad * 4;
  const int c0 = tile_n + wn * 64 + l15;
  const bool isGate = (tile_n >= 3072);  // block-uniform (3072 % 128 == 0)
  const float* bp = isGate ? bgate : bqkv;
  const int crel0 = isGate ? (c0 - 3072) : c0;
  const int nout = isGate ? 1024 : 3072;
  u16* outp = isGate ? gateb : qkvb;
#pragma unroll
  for (int mi = 0; mi < 4; ++mi) {
#pragma unroll
    for (int ni = 0; ni < 4; ++ni) {
      int col = crel0 + ni * 16;
      float bv = bp[col];
#pragma unroll
      for (int r = 0; r < 4; ++r) {
        float val = acc[mi][ni][r] + bv;
        if (isGate) val = 1.f / (1.f + __expf(-val));
        outp[(size_t)(r0 + mi * 16 + r) * nout + col] = f2bf(val);
      }
    }
  }
}

// ---------------- out GEMM: out = a2 @ Wout^T + bout (fp32) ----------------
// 64x64 tiles, BK=128, grid (16,32) = 512 blocks = 2 blocks/CU (r7 had
// 128x64 / 256 blocks = 1 block/CU = 1 wave/SIMD, no latency hiding).
// Wave w owns rows [w*16, w*16+16) x 64 cols (acc 1x4).
__global__ __launch_bounds__(256) void gemm_out(
    const u16* __restrict__ A, const u16* __restrict__ B,
    const float* __restrict__ bias, float* __restrict__ C) {
  __shared__ __align__(16) u16 As[64 * 128];
  __shared__ __align__(16) u16 Bs[64 * 128];
  const int tid = threadIdx.x;
  const int lane = tid & 63;
  const int w = tid >> 6;
  const int tile_m = blockIdx.y * 64;
  const int tile_n = blockIdx.x * 64;
  const int l15 = lane & 15;
  const int quad = lane >> 4;

  f32x4 acc[4];
  const f32x4 zero = {0.f, 0.f, 0.f, 0.f};
#pragma unroll
  for (int ni = 0; ni < 4; ++ni) acc[ni] = zero;

  for (int k0 = 0; k0 < 1024; k0 += 128) {
#pragma unroll
    for (int c = 0; c < 4; ++c) {
      int idx = c * 256 + tid;
      int row = idx >> 4;
      int gcol = ((idx & 15) ^ (row & 15)) * 8;
      int lcol = (idx & 15) * 8;
      async16(A + (size_t)(tile_m + row) * 1024 + k0 + gcol, As + row * 128 + lcol);
      async16(B + (size_t)(tile_n + row) * 1024 + k0 + gcol, Bs + row * 128 + lcol);
    }
    __syncthreads();

#pragma unroll
    for (int kk = 0; kk < 4; ++kk) {
      const int pc = ((kk * 4 + quad) ^ l15) * 8;
      bf16x8 af = *(const bf16x8*)(As + (w * 16 + l15) * 128 + pc);
      bf16x8 bfr[4];
#pragma unroll
      for (int ni = 0; ni < 4; ++ni)
        bfr[ni] = *(const bf16x8*)(Bs + (ni * 16 + l15) * 128 + pc);
#pragma unroll
      for (int ni = 0; ni < 4; ++ni)
        acc[ni] = __builtin_amdgcn_mfma_f32_16x16x32_bf16(af, bfr[ni], acc[ni], 0, 0, 0);
    }
    __syncthreads();
  }

  const int r0 = tile_m + w * 16 + quad * 4;
  const int c0 = tile_n + l15;
#pragma unroll
  for (int ni = 0; ni < 4; ++ni) {
    int col = c0 + ni * 16;
    float bv = bias[col];
#pragma unroll
    for (int r = 0; r < 4; ++r)
      C[(size_t)(r0 + r) * 1024 + col] = acc[ni][r] + bv;
  }
}

// ---------------- MFMA attention (r3 version) ----------------
__global__ __launch_bounds__(256) void attn_mfma_kernel(
    const u16* __restrict__ qkv, const float* __restrict__ pos_bias,
    const u16* __restrict__ gate, u16* __restrict__ a2) {
  __shared__ __align__(16) u16 Pl[4][16][232];
  __shared__ float pbs[NOFF];
  const int tid = threadIdx.x;
  const int lane = tid & 63;
  const int w = tid >> 6;
  const int h = blockIdx.y;
  const int n0 = blockIdx.x * 64 + w * 16;
  const int quad = lane >> 4;
  const int l15 = lane & 15;

  if (tid < NOFF) pbs[tid] = pos_bias[tid * NHEAD + h];

  const int soffs[11] = {48, 64, 96, 128, 192, 256, 384, 512, 768, 1024, 1536};
  int gbase[14];
  gbase[0] = n0 - 32; gbase[1] = n0 - 16; gbase[2] = n0;
#pragma unroll
  for (int g = 0; g < 11; ++g) gbase[3 + g] = n0 - soffs[g];

  const u16* qbase = qkv + (size_t)(n0 + l15) * 3072 + h * 64 + quad * 8;
  bf16x8 aq0 = *(const bf16x8*)(qbase);
  bf16x8 aq1 = *(const bf16x8*)(qbase + 32);

  f32x4 s[14];
  const f32x4 zero = {0.f, 0.f, 0.f, 0.f};
#pragma unroll
  for (int g = 0; g < 14; ++g) {
    s[g] = zero;
    if (gbase[g] + 15 < 0) continue;
    int row = gbase[g] + l15;
    int rc = row < 0 ? 0 : row;
    const u16* kb = qkv + 1024 + (size_t)rc * 3072 + h * 64 + quad * 8;
    bf16x8 bk0 = *(const bf16x8*)(kb);
    bf16x8 bk1 = *(const bf16x8*)(kb + 32);
    s[g] = __builtin_amdgcn_mfma_f32_16x16x32_bf16(aq0, bk0, s[g], 0, 0, 0);
    s[g] = __builtin_amdgcn_mfma_f32_16x16x32_bf16(aq1, bk1, s[g], 0, 0, 0);
  }
  __syncthreads();  // pbs ready

#pragma unroll
  for (int g = 0; g < 14; ++g) {
    int key = gbase[g] + l15;
#pragma unroll
    for (int r = 0; r < 4; ++r) {
      int q = n0 + quad * 4 + r;
      int o = q - key;
      bool valid; int bidx;
      if (g < 3) {
        valid = (o >= 0) & (o <= 32) & (key >= 0);
        bidx = o < 0 ? 0 : (o > 32 ? 32 : o);
      } else {
        valid = (key >= 0) & (o == soffs[g - 3]);
        bidx = g + 30;
      }
      float val = s[g][r] * 0.125f + pbs[bidx];
      s[g][r] = valid ? val : -INFINITY;
    }
  }

  float rl[4];
#pragma unroll
  for (int r = 0; r < 4; ++r) {
    float mx = s[0][r];
#pragma unroll
    for (int g = 1; g < 14; ++g) mx = fmaxf(mx, s[g][r]);
    mx = fmaxf(mx, __shfl_xor(mx, 1, 64));
    mx = fmaxf(mx, __shfl_xor(mx, 2, 64));
    mx = fmaxf(mx, __shfl_xor(mx, 4, 64));
    mx = fmaxf(mx, __shfl_xor(mx, 8, 64));
    float sum = 0.f;
#pragma unroll
    for (int g = 0; g < 14; ++g) {
      float p = __expf(s[g][r] - mx);
      s[g][r] = p;
      sum += p;
    }
    sum += __shfl_xor(sum, 1, 64);
    sum += __shfl_xor(sum, 2, 64);
    sum += __shfl_xor(sum, 4, 64);
    sum += __shfl_xor(sum, 8, 64);
    rl[r] = 1.0f / sum;
  }

#pragma unroll
  for (int g = 0; g < 14; ++g)
#pragma unroll
    for (int r = 0; r < 4; ++r)
      Pl[w][quad * 4 + r][g * 16 + l15] = f2bf(s[g][r]);
  __syncthreads();

  f32x4 ov[4];
#pragma unroll
  for (int ni = 0; ni < 4; ++ni) ov[ni] = zero;
  const u16* vb = qkv + 2048 + h * 64;
#pragma unroll
  for (int kc = 0; kc < 7; ++kc) {
    if (gbase[2 * kc] + 15 < 0 && gbase[2 * kc + 1] + 15 < 0) continue;
    bf16x8 ap = *(const bf16x8*)(&Pl[w][l15][kc * 32 + quad * 8]);
    int g = kc * 2 + (quad >> 1);
    int keyg = gbase[g] + (quad & 1) * 8;
    const u16* rp[8];
#pragma unroll
    for (int j = 0; j < 8; ++j) {
      int row = keyg + j;
      rp[j] = vb + (size_t)(row < 0 ? 0 : row) * 3072;
    }
#pragma unroll
    for (int ni = 0; ni < 4; ++ni) {
      bf16x8 bv;
#pragma unroll
      for (int j = 0; j < 8; ++j) bv[j] = (short)rp[j][ni * 16 + l15];
      ov[ni] = __builtin_amdgcn_mfma_f32_16x16x32_bf16(ap, bv, ov[ni], 0, 0, 0);
    }
  }

#pragma unroll
  for (int ni = 0; ni < 4; ++ni) {
#pragma unroll
    for (int r = 0; r < 4; ++r) {
      int q = n0 + quad * 4 + r;
      int col = h * 64 + ni * 16 + l15;
      float o = ov[ni][r] * rl[r];
      float g = bf2f(gate[(size_t)q * DMODEL + col]);
      a2[(size_t)q * DMODEL + col] = f2bf(o * g);
    }
  }
}

extern "C" void kernel_launch(void* const* d_in, const int* in_sizes, int n_in,
                              void* d_out, int out_size, void* d_ws,
                              size_t ws_size, hipStream_t stream) {
  (void)in_sizes; (void)n_in; (void)out_size; (void)ws_size;
  const float* x = (const float*)d_in[0];
  const float* Wqkv = (const float*)d_in[1];
  const float* bqkv = (const float*)d_in[2];
  const float* Wout = (const float*)d_in[3];
  const float* bout = (const float*)d_in[4];
  const float* Wgate = (const float*)d_in[5];
  const float* bgate = (const float*)d_in[6];
  const float* pos_bias = (const float*)d_in[7];
  float* out = (float*)d_out;

  char* ws = (char*)d_ws;
  u16* xb    = (u16*)(ws);                    // [2048,1024]  4 MB
  u16* Wcat  = (u16*)(ws + (4u << 20));       // [4096,1024]  8 MB (Wqkv|Wgate)
  u16* Woutb = (u16*)(ws + (12u << 20));      // [1024,1024]  2 MB
  u16* qkvb  = (u16*)(ws + (14u << 20));      // [2048,3072] 12 MB
  u16* gate  = (u16*)(ws + (26u << 20));      // [2048,1024]  4 MB bf16
  u16* a2    = (u16*)(ws + (30u << 20));      // [2048,1024]  4 MB

  cvt_all_kernel<<<7168, 256, 0, stream>>>(
      x, Wqkv, Wgate, Wout, xb, Wcat, Wcat + 3072 * 1024, Woutb);

  // [qkv | gate] = x @ [Wqkv;Wgate]^T
  gemm_fused<<<dim3(32, 16), 256, 0, stream>>>(xb, Wcat, bqkv, bgate,
                                               qkvb, gate);
  // attention + gating -> a2 bf16 [2048, 1024]
  attn_mfma_kernel<<<dim3(32, 16), 256, 0, stream>>>(qkvb, pos_bias, gate, a2);
  // out = a2 @ Wout^T + bout -> fp32 [2048, 1024]
  gemm_out<<<dim3(16, 32), 256, 0, stream>>>(a2, Woutb, bout, out);
}